// Round 5
// baseline (487.981 us; speedup 1.0000x reference)
//
#include <hip/hip_runtime.h>
#include <math.h>

// Problem constants
#define NP 8836          // number of patches per image (94*94)
#define PW 94            // patches per row
#define IW 96            // image width/height
#define CH 256           // channels
#define NTILE 70         // ceil(8836/128)
#define KT2 18           // K tiles: 2304/128 (BK=128)
#define NWG (NTILE * NTILE)   // 4900 blocks

typedef int   i32x4  __attribute__((ext_vector_type(4)));
typedef int   i32x8  __attribute__((ext_vector_type(8)));
typedef float f32x16 __attribute__((ext_vector_type(16)));

__device__ __forceinline__ unsigned int ordf(float f) {
  unsigned int u = __float_as_uint(f);
  return (u & 0x80000000u) ? ~u : (u | 0x80000000u);
}

typedef const __attribute__((address_space(1))) void GvoidC;
typedef __attribute__((address_space(3))) void Lvoid;
__device__ __forceinline__ void gl16(const void* g, void* l) {
  __builtin_amdgcn_global_load_lds((GvoidC*)g, (Lvoid*)l, 16, 0, 0);
}

// ---------------------------------------------------------------------------
// 1) Convert+transpose [C, 9216] fp32 -> [9216, C] fp8 (HW v_cvt encoding).
// ---------------------------------------------------------------------------
__global__ __launch_bounds__(256) void prep_kernel(
    const float* __restrict__ inA, const float* __restrict__ inB,
    unsigned int* __restrict__ TA, unsigned int* __restrict__ TB) {
  __shared__ float tile[64][65];
  int bid = blockIdx.x;            // [0, 1152)
  const float* src; unsigned int* dst;
  if (bid < 576) { src = inA; dst = TA; }
  else           { src = inB; dst = TB; bid -= 576; }
  int cT  = bid & 3;        // c-tile   [0,4)  (64 channels)
  int xyT = bid >> 2;       // xy-tile  [0,144)
  int t = threadIdx.x;
  int l = t & 63, h = t >> 6;

  #pragma unroll
  for (int i = 0; i < 16; ++i) {
    int c = h * 16 + i;
    tile[c][l] = src[(size_t)(cT * 64 + c) * (IW * IW) + xyT * 64 + l];
  }
  __syncthreads();
  int cu = t & 15;          // u32 column within the 64-channel tile
  #pragma unroll
  for (int i = 0; i < 4; ++i) {
    int xy = (t >> 4) + i * 16;
    int c = cu * 4;
    unsigned int v = __builtin_amdgcn_cvt_pk_fp8_f32(tile[c][xy],     tile[c + 1][xy], 0, false);
    v              = __builtin_amdgcn_cvt_pk_fp8_f32(tile[c + 2][xy], tile[c + 3][xy], v, true);
    dst[(size_t)(xyT * 64 + xy) * 64 + cT * 16 + cu] = v;
  }
}

// ---------------------------------------------------------------------------
// 2) Per-patch squared norms from the fp8 images (consistent with GEMM dtype).
// ---------------------------------------------------------------------------
__global__ void norms_kernel(const unsigned int* __restrict__ TA, const unsigned int* __restrict__ TB,
                             float* __restrict__ rnormS, float* __restrict__ normS,
                             float* __restrict__ normsqS, float* __restrict__ synsq) {
  int wid  = blockIdx.x * 4 + (threadIdx.x >> 6);
  int lane = threadIdx.x & 63;
  bool isStyle = wid < NP;
  int p = isStyle ? wid : wid - NP;
  if (p >= NP) return;
  const unsigned int* T = isStyle ? TB : TA;
  int pi = p / PW, pj = p % PW;
  float s = 0.f;
  #pragma unroll
  for (int kh = 0; kh < 3; ++kh) {
    #pragma unroll
    for (int kw = 0; kw < 3; ++kw) {
      unsigned int v = T[(size_t)((pi + kh) * IW + (pj + kw)) * 64 + lane];
      float f0 = __builtin_amdgcn_cvt_f32_fp8(v, 0);
      float f1 = __builtin_amdgcn_cvt_f32_fp8(v, 1);
      float f2 = __builtin_amdgcn_cvt_f32_fp8(v, 2);
      float f3 = __builtin_amdgcn_cvt_f32_fp8(v, 3);
      s += f0 * f0 + f1 * f1 + f2 * f2 + f3 * f3;
    }
  }
  #pragma unroll
  for (int m = 32; m >= 1; m >>= 1) s += __shfl_xor(s, m, 64);
  if (lane == 0) {
    if (isStyle) {
      normsqS[p] = s;
      float n = sqrtf(s);
      normS[p]  = n;
      rnormS[p] = 1.f / n;
    } else {
      synsq[p] = s;
    }
  }
}

// ---------------------------------------------------------------------------
// 3) MX-fp8 implicit-im2col GEMM, 128x128 tile, BK=128 (18 iters),
//    mfma_scale_f32_32x32x64_f8f6f4 x8 per iter per wave, unit scales.
//    R5 structure: B through LDS (16 KB, single-buffered, chunk-XOR swizzle),
//    A DIRECT global->VGPR (no LDS round-trip).
//    Rationale (R4 post-mortem): at 13 waves/CU the LDS pipe was the top
//    resource (~55% busy: A+B reads 5.64 GB at 85 B/cy b128 throughput +
//    2.82 GB DMA writes) while MFMA sat at 30%. A-fragment rows are
//    wave-private and TA (2.4 MB) is L2-resident (R4's XCD swizzle halved
//    HBM fetch), so A-frags load straight to registers: LDS traffic halves,
//    MFMA becomes the top pipe (~189k cy/CU floor).
//    A-frag loads are issued together with the B global_load_lds, so their
//    L2 latency hides under the same pre-barrier vmcnt drain.
//    LDS B: row stride 128 B; chunk-XOR swizzle (slot = chunk ^ (row&7));
//    staging pre-swizzles the GLOBAL source chunk so the LDS dest stays
//    linear (global_load_lds wave-uniform-base requirement).
// ---------------------------------------------------------------------------
__device__ __forceinline__ i32x8 ld2x16(const unsigned char* p0, const unsigned char* p1) {
  i32x4 lo = *(const i32x4*)p0;
  i32x4 hi = *(const i32x4*)p1;
  return __builtin_shufflevector(lo, hi, 0, 1, 2, 3, 4, 5, 6, 7);
}

__global__ __launch_bounds__(256, 3) void gemm_argmax_kernel(
    const unsigned char* __restrict__ TA, const unsigned char* __restrict__ TB,
    const float* __restrict__ rnormS, unsigned long long* __restrict__ best) {
  __shared__ unsigned char Bs[128 * 128];   // 16 KB, B-panel only

  // Bijective XCD-chunked swizzle (nwg=4900, nxcd=8: q=612, r=4): each XCD
  // gets a contiguous wgid chunk -> contiguous nt values -> panels stay in
  // that XCD's 4MB L2 (R4: FETCH_SIZE 18.6->10.8 MB, kept for A-direct L2 hits).
  int orig = blockIdx.x;
  int xcd = orig & 7, idx = orig >> 3;
  int pid = (xcd < 4 ? xcd * 613 : 4 * 613 + (xcd - 4) * 612) + idx;

  int mt = pid % NTILE, nt = pid / NTILE;
  int q0 = mt * 128, s0 = nt * 128;
  int t = threadIdx.x, lane = t & 63, wave = t >> 6;
  int wm = wave >> 1, wn = wave & 1;

  // B staging: instruction i (0..3) of thread t writes LDS offset i*4096+t*16,
  // i.e. row 32i + (t>>3), slot t&7. It must fetch global chunk
  // qc = (t&7) ^ ((t>>3)&7)  (row bits 0-2 are i-invariant).
  int rr = t >> 3;
  int qc = (t & 7) ^ (rr & 7);
  const unsigned char* gB[4];
  #pragma unroll
  for (int i = 0; i < 4; ++i) {
    int sa = s0 + 32 * i + rr; if (sa > NP - 1) sa = NP - 1;
    gB[i] = TB + (size_t)((sa / PW) * IW + (sa % PW)) * CH + qc * 16;
  }
  unsigned char* lB = Bs + t * 16;

  // A-fragment layout for 32x32x64: lane l holds row (l&31) of the wave's
  // 32-row sub-tile, K-bytes (l>>5)*32 + h*64 .. +32 of the 128-B K-step.
  // Direct-global base per mi (chunks are LINEAR in global — no XOR there):
  int kq = lane >> 5, sw = lane & 7;
  const unsigned char* gAf[2];
  #pragma unroll
  for (int mi = 0; mi < 2; ++mi) {
    int ra = q0 + wm * 64 + mi * 32 + (lane & 31); if (ra > NP - 1) ra = NP - 1;
    gAf[mi] = TA + (size_t)((ra / PW) * IW + (ra % PW)) * CH + kq * 32;
  }

  f32x16 acc[2][2];
  #pragma unroll
  for (int mi = 0; mi < 2; ++mi)
    #pragma unroll
    for (int ni = 0; ni < 2; ++ni)
      #pragma unroll
      for (int j = 0; j < 16; ++j)
        acc[mi][ni][j] = 0.f;

  // B fragment reads from LDS: row = wn*64 + ni*32 + (lane&31), stride 128 B.
  // k-half h: logical chunks c0 = 2*kq+4h, c0+1; slots = c ^ (lane&7).
  const unsigned char* Brow = Bs + (size_t)(wn * 64 + (lane & 31)) * 128;

  #pragma unroll 1
  for (int kt = 0; kt < KT2; ++kt) {
    int chunk = kt >> 1;                 // which (kh,kw) of 9
    int kh = chunk / 3, kw = chunk - kh * 3;
    int choff = (kh * IW + kw) * CH + (kt & 1) * 128;   // bytes
    if (kt) __syncthreads();             // barrier#1: Bs reads of prev step done
    #pragma unroll
    for (int i = 0; i < 4; ++i) gl16(gB[i] + choff, lB + i * 4096);
    // A-frags for THIS step, issued alongside the B DMA so both latencies
    // drain under the same pre-barrier vmcnt(0).
    i32x8 af[2][2];
    #pragma unroll
    for (int mi = 0; mi < 2; ++mi)
      #pragma unroll
      for (int h = 0; h < 2; ++h) {
        const unsigned char* p = gAf[mi] + choff + h * 64;
        af[mi][h] = ld2x16(p, p + 16);
      }
    __syncthreads();                     // vmcnt(0) drain + barrier#2

    #pragma unroll
    for (int h = 0; h < 2; ++h) {
      int c0 = 2 * kq + 4 * h;
      int o0 = (c0 ^ sw) * 16, o1 = ((c0 + 1) ^ sw) * 16;
      i32x8 bf[2];
      #pragma unroll
      for (int ni = 0; ni < 2; ++ni)
        bf[ni] = ld2x16(Brow + ni * 32 * 128 + o0, Brow + ni * 32 * 128 + o1);
      #pragma unroll
      for (int mi = 0; mi < 2; ++mi)
        #pragma unroll
        for (int ni = 0; ni < 2; ++ni)
          acc[mi][ni] = __builtin_amdgcn_mfma_scale_f32_32x32x64_f8f6f4(
              af[mi][h], bf[ni], acc[mi][ni],
              0, 0,                       // A fmt = fp8(e4m3), B fmt = fp8
              0, 0x7F7F7F7F,              // opsel_a, scale_a = 1.0
              0, 0x7F7F7F7F);             // opsel_b, scale_b = 1.0
    }
  }

  // Epilogue. C/D layout (32x32): col = lane&31, row = (reg&3)+8*(reg>>2)+4*(lane>>5).
  // best[] padded to 64 B per q (stride 8 u64): each q owns a cacheline.
  int col = lane & 31, half = lane >> 5;
  float rn[2]; int sc[2]; bool sv[2];
  #pragma unroll
  for (int ni = 0; ni < 2; ++ni) {
    int s = s0 + wn * 64 + ni * 32 + col;
    sc[ni] = s;
    sv[ni] = (s < NP);
    rn[ni] = sv[ni] ? rnormS[s] : 0.f;
  }
  #pragma unroll
  for (int mi = 0; mi < 2; ++mi) {
    #pragma unroll
    for (int reg = 0; reg < 16; ++reg) {
      unsigned long long p = 0ull;
      #pragma unroll
      for (int ni = 0; ni < 2; ++ni) {
        float v = acc[mi][ni][reg] * rn[ni];
        unsigned long long cand =
            ((unsigned long long)ordf(v) << 32) |
            (unsigned long long)(0xFFFFFFFFu - (unsigned)sc[ni]);
        cand = sv[ni] ? cand : 0ull;
        if (cand > p) p = cand;
      }
      #pragma unroll
      for (int sh = 16; sh >= 1; sh >>= 1) {   // reduce within each 32-lane half
        unsigned long long o = __shfl_xor(p, sh, 64);
        if (o > p) p = o;
      }
      int q = q0 + wm * 64 + mi * 32 + (reg & 3) + 8 * (reg >> 2) + 4 * half;
      if (col == 0 && q < NP) atomicMax(best + (size_t)q * 8, p);
    }
  }
}

// ---------------------------------------------------------------------------
// 4) Final loss: loss = mean_q (synsq[q] - 2*dot + normsq[nn]) / 2304
// ---------------------------------------------------------------------------
__global__ void finalize_kernel(const unsigned long long* __restrict__ best,
                                const float* __restrict__ normS,
                                const float* __restrict__ normsqS,
                                const float* __restrict__ synsq,
                                float* __restrict__ out) {
  __shared__ float sm[256];
  int t = threadIdx.x;
  float accum = 0.f;
  for (int q = t; q < NP; q += 256) {
    unsigned long long p = best[(size_t)q * 8];
    unsigned int o   = (unsigned int)(p >> 32);
    unsigned int idx = 0xFFFFFFFFu - (unsigned int)(p & 0xFFFFFFFFull);
    unsigned int u   = (o & 0x80000000u) ? (o & 0x7FFFFFFFu) : ~o;
    float resp = __uint_as_float(u);
    float dot  = resp * normS[idx];
    accum += synsq[q] - 2.f * dot + normsqS[idx];
  }
  sm[t] = accum;
  __syncthreads();
  for (int s = 128; s >= 1; s >>= 1) {
    if (t < s) sm[t] += sm[t + s];
    __syncthreads();
  }
  if (t == 0) out[0] = sm[0] / ((float)NP * 2304.f);
}

// ---------------------------------------------------------------------------
extern "C" void kernel_launch(void* const* d_in, const int* in_sizes, int n_in,
                              void* d_out, int out_size, void* d_ws, size_t ws_size,
                              hipStream_t stream) {
  const float* inA = (const float*)d_in[0];  // input  (synthesis)
  const float* inB = (const float*)d_in[1];  // target (style)
  float* out = (float*)d_out;

  char* ws = (char*)d_ws;
  unsigned char* TA = (unsigned char*)ws;                 // 2,359,296 B fp8
  unsigned char* TB = (unsigned char*)(ws + 2359296);     // 2,359,296 B fp8
  float* rnormS  = (float*)(ws + 4718592);
  float* normS   = (float*)(ws + 4718592 + 35344);
  float* normsqS = (float*)(ws + 4718592 + 70688);
  float* synsq   = (float*)(ws + 4718592 + 106032);
  unsigned long long* best = (unsigned long long*)(ws + 4718592 + 141376);
  // best is padded: 64 B (8 u64) per q -> 565,504 B total.

  (void)hipMemsetAsync(best, 0, (size_t)NP * 64, stream);
  prep_kernel<<<dim3(1152), dim3(256), 0, stream>>>(inA, inB, (unsigned int*)TA, (unsigned int*)TB);
  norms_kernel<<<dim3((2 * NP + 3) / 4), dim3(256), 0, stream>>>(
      (const unsigned int*)TA, (const unsigned int*)TB, rnormS, normS, normsqS, synsq);
  gemm_argmax_kernel<<<dim3(NWG), dim3(256), 0, stream>>>(TA, TB, rnormS, best);
  finalize_kernel<<<dim3(1), dim3(256), 0, stream>>>(best, normS, normsqS, synsq, out);
}

// Round 6
// 267.235 us; speedup vs baseline: 1.8260x; 1.8260x over previous
//
#include <hip/hip_runtime.h>
#include <math.h>

// Problem constants
#define NP 8836          // number of patches per image (94*94)
#define PW 94            // patches per row
#define IW 96            // image width/height
#define CH 256           // channels
#define NTILE 70         // ceil(8836/128)  (fallback GEMM)
#define KT2 18           // fallback K tiles
#define NWG (NTILE * NTILE)
#define NPIX 9216        // 96*96 pixels
#define GTS 9216         // GT row stride in elements

typedef int   i32x4  __attribute__((ext_vector_type(4)));
typedef int   i32x8  __attribute__((ext_vector_type(8)));
typedef float f32x16 __attribute__((ext_vector_type(16)));

__device__ __forceinline__ unsigned int ordf(float f) {
  unsigned int u = __float_as_uint(f);
  return (u & 0x80000000u) ? ~u : (u | 0x80000000u);
}

typedef const __attribute__((address_space(1))) void GvoidC;
typedef __attribute__((address_space(3))) void Lvoid;
__device__ __forceinline__ void gl16(const void* g, void* l) {
  __builtin_amdgcn_global_load_lds((GvoidC*)g, (Lvoid*)l, 16, 0, 0);
}

// ---------------------------------------------------------------------------
// 1) Convert+transpose [C, 9216] fp32 -> [9216, C] fp8 (HW v_cvt encoding).
// ---------------------------------------------------------------------------
__global__ __launch_bounds__(256) void prep_kernel(
    const float* __restrict__ inA, const float* __restrict__ inB,
    unsigned int* __restrict__ TA, unsigned int* __restrict__ TB) {
  __shared__ float tile[64][65];
  int bid = blockIdx.x;            // [0, 1152)
  const float* src; unsigned int* dst;
  if (bid < 576) { src = inA; dst = TA; }
  else           { src = inB; dst = TB; bid -= 576; }
  int cT  = bid & 3;        // c-tile   [0,4)  (64 channels)
  int xyT = bid >> 2;       // xy-tile  [0,144)
  int t = threadIdx.x;
  int l = t & 63, h = t >> 6;

  #pragma unroll
  for (int i = 0; i < 16; ++i) {
    int c = h * 16 + i;
    tile[c][l] = src[(size_t)(cT * 64 + c) * (IW * IW) + xyT * 64 + l];
  }
  __syncthreads();
  int cu = t & 15;          // u32 column within the 64-channel tile
  #pragma unroll
  for (int i = 0; i < 4; ++i) {
    int xy = (t >> 4) + i * 16;
    int c = cu * 4;
    unsigned int v = __builtin_amdgcn_cvt_pk_fp8_f32(tile[c][xy],     tile[c + 1][xy], 0, false);
    v              = __builtin_amdgcn_cvt_pk_fp8_f32(tile[c + 2][xy], tile[c + 3][xy], v, true);
    dst[(size_t)(xyT * 64 + xy) * 64 + cT * 16 + cu] = v;
  }
}

// ---------------------------------------------------------------------------
// 2) Per-patch squared norms from the fp8 images (consistent with GEMM dtype).
// ---------------------------------------------------------------------------
__global__ void norms_kernel(const unsigned int* __restrict__ TA, const unsigned int* __restrict__ TB,
                             float* __restrict__ rnormS, float* __restrict__ normS,
                             float* __restrict__ normsqS, float* __restrict__ synsq) {
  int wid  = blockIdx.x * 4 + (threadIdx.x >> 6);
  int lane = threadIdx.x & 63;
  bool isStyle = wid < NP;
  int p = isStyle ? wid : wid - NP;
  if (p >= NP) return;
  const unsigned int* T = isStyle ? TB : TA;
  int pi = p / PW, pj = p % PW;
  float s = 0.f;
  #pragma unroll
  for (int kh = 0; kh < 3; ++kh) {
    #pragma unroll
    for (int kw = 0; kw < 3; ++kw) {
      unsigned int v = T[(size_t)((pi + kh) * IW + (pj + kw)) * 64 + lane];
      float f0 = __builtin_amdgcn_cvt_f32_fp8(v, 0);
      float f1 = __builtin_amdgcn_cvt_f32_fp8(v, 1);
      float f2 = __builtin_amdgcn_cvt_f32_fp8(v, 2);
      float f3 = __builtin_amdgcn_cvt_f32_fp8(v, 3);
      s += f0 * f0 + f1 * f1 + f2 * f2 + f3 * f3;
    }
  }
  #pragma unroll
  for (int m = 32; m >= 1; m >>= 1) s += __shfl_xor(s, m, 64);
  if (lane == 0) {
    if (isStyle) {
      normsqS[p] = s;
      float n = sqrtf(s);
      normS[p]  = n;
      rnormS[p] = 1.f / n;
    } else {
      synsq[p] = s;
    }
  }
}

__device__ __forceinline__ i32x8 ldfrag(const unsigned char* rowp, int o0, int o1) {
  i32x4 lo = *(const i32x4*)(rowp + o0);
  i32x4 hi = *(const i32x4*)(rowp + o1);
  return __builtin_shufflevector(lo, hi, 0, 1, 2, 3, 4, 5, 6, 7);
}

// ---------------------------------------------------------------------------
// 3a) G-path kernel 1: pixel Gram GT[y][x] = sum_ch TB[y][ch]*TA[x][ch],
//     M=N=9216, K=256 (2 BK=128 steps), 128x128 tiles (72x72 grid), bf16 out.
//     Exact R0 K-loop shape (proven): chunk-XOR LDS swizzle, gl16 staging.
//     8.3x fewer FLOPs than the direct patch GEMM (43.5 vs 360 GFLOP):
//     stride-1 3x3 patches make resp a 9-tap diagonal sum over G.
// ---------------------------------------------------------------------------
__global__ __launch_bounds__(256, 2) void g_gemm_kernel(
    const unsigned char* __restrict__ TA, const unsigned char* __restrict__ TB,
    unsigned short* __restrict__ GT) {
  __shared__ unsigned char As[128 * 128];
  __shared__ unsigned char Bs[128 * 128];

  // XCD-chunked bijective swizzle: 5184 = 8*648.
  int orig = blockIdx.x;
  int pid = (orig & 7) * 648 + (orig >> 3);
  int yt = pid % 72, xt = pid / 72;     // per-XCD chunk = 9 xt panels:
  int y0 = yt * 128, x0 = xt * 128;     // TB(2.4MB)+9 TA panels fit 4MB L2.
  int t = threadIdx.x, lane = t & 63, wave = t >> 6;
  int wm = wave >> 1, wn = wave & 1;

  int rr = t >> 3;
  int qc = (t & 7) ^ (rr & 7);
  const unsigned char* gA[4];
  const unsigned char* gB[4];
  #pragma unroll
  for (int i = 0; i < 4; ++i) {
    gA[i] = TB + (size_t)(y0 + 32 * i + rr) * CH + qc * 16;   // A-op = style y
    gB[i] = TA + (size_t)(x0 + 32 * i + rr) * CH + qc * 16;   // B-op = synth x
  }
  unsigned char* lA = As + t * 16;
  unsigned char* lB = Bs + t * 16;

  f32x16 acc[2][2];
  #pragma unroll
  for (int mi = 0; mi < 2; ++mi)
    #pragma unroll
    for (int ni = 0; ni < 2; ++ni)
      #pragma unroll
      for (int j = 0; j < 16; ++j) acc[mi][ni][j] = 0.f;

  int kq = lane >> 5, sw = lane & 7;
  const unsigned char* Arow = As + (size_t)(wm * 64 + (lane & 31)) * 128;
  const unsigned char* Brow = Bs + (size_t)(wn * 64 + (lane & 31)) * 128;

  #pragma unroll 1
  for (int kt = 0; kt < 2; ++kt) {
    int choff = kt * 128;
    if (kt) __syncthreads();
    #pragma unroll
    for (int i = 0; i < 4; ++i) {
      gl16(gA[i] + choff, lA + i * 4096);
      gl16(gB[i] + choff, lB + i * 4096);
    }
    __syncthreads();
    #pragma unroll
    for (int h = 0; h < 2; ++h) {
      int c0 = 2 * kq + 4 * h;
      int o0 = (c0 ^ sw) * 16, o1 = ((c0 + 1) ^ sw) * 16;
      i32x8 af[2], bf[2];
      #pragma unroll
      for (int mi = 0; mi < 2; ++mi) af[mi] = ldfrag(Arow + mi * 32 * 128, o0, o1);
      #pragma unroll
      for (int ni = 0; ni < 2; ++ni) bf[ni] = ldfrag(Brow + ni * 32 * 128, o0, o1);
      #pragma unroll
      for (int mi = 0; mi < 2; ++mi)
        #pragma unroll
        for (int ni = 0; ni < 2; ++ni)
          acc[mi][ni] = __builtin_amdgcn_mfma_scale_f32_32x32x64_f8f6f4(
              af[mi], bf[ni], acc[mi][ni],
              0, 0, 0, 0x7F7F7F7F, 0, 0x7F7F7F7F);
    }
  }

  // Epilogue: C/D (32x32): col = lane&31, row = (reg&3)+8*(reg>>2)+4*(lane>>5).
  // Store bf16 (RNE via integer round), coalesced ushort stores along x.
  int col = lane & 31, half = lane >> 5;
  #pragma unroll
  for (int mi = 0; mi < 2; ++mi) {
    #pragma unroll
    for (int ni = 0; ni < 2; ++ni) {
      size_t ybase = (size_t)(y0 + wm * 64 + mi * 32 + 4 * half);
      size_t xg    = (size_t)(x0 + wn * 64 + ni * 32 + col);
      unsigned short* p = GT + ybase * GTS + xg;
      #pragma unroll
      for (int g = 0; g < 4; ++g)
        #pragma unroll
        for (int j = 0; j < 4; ++j) {
          unsigned int u = __float_as_uint(acc[mi][ni][4 * g + j]);
          unsigned short b = (unsigned short)((u + 0x7FFFu + ((u >> 16) & 1u)) >> 16);
          p[(size_t)(j + 8 * g) * GTS] = b;
        }
    }
  }
}

// ---------------------------------------------------------------------------
// 3b) G-path kernel 2: tap-sum + argmax.
//     resp[(qi,qj),(si,sj)] = sum_{dh,dw} GT[(si+dh)*96 + sj+dw]
//                                            [(qi+dh)*96 + qj+dw]
//     Block = one (qi,si) patch-row pair (8836 blocks). Lanes along qj
//     (coalesced 128B rows); loop over sj; per-lane running argmax (no
//     per-iter cross-lane reduce). Diagonal-major block order: G-rows of
//     (qi,si) are reused by (qi+1,si+1),(qi+2,si+2) = adjacent blocks ->
//     L2-hot. u32 element offsets coax saddr+voffset addressing.
// ---------------------------------------------------------------------------
__global__ __launch_bounds__(256) void tapsum_kernel(
    const unsigned short* __restrict__ GT, const float* __restrict__ rnormS,
    unsigned long long* __restrict__ best) {
  __shared__ unsigned long long sm[2][128];
  // XCD-chunked bijective swizzle (m204): nwg=8836, q=1104, r=4.
  int orig = blockIdx.x;
  int xcd = orig & 7, idx = orig >> 3;
  int pid = (xcd < 4 ? xcd * 1105 : 4 * 1105 + (xcd - 4) * 1104) + idx;
  // Diagonal-major: consecutive pid -> (qi+1, si+1): shares 2/3 G row-bands.
  int d = pid / 94, pos = pid - d * 94;
  int qi = pos;
  int si = pos + d; if (si >= 94) si -= 94;

  int t = threadIdx.x;
  int qj = t & 127, halfv = t >> 7;      // wave-uniform halfv
  bool active = qj < 94;
  int qjc = active ? qj : 93;            // clamp: keeps addresses in-bounds
  int sj0 = halfv * 47;

  unsigned int off[9];
  #pragma unroll
  for (int dh = 0; dh < 3; ++dh)
    #pragma unroll
    for (int dw = 0; dw < 3; ++dw)
      off[dh * 3 + dw] = (unsigned)(((si + dh) * 96 + sj0 + dw) * GTS
                                    + (qi + dh) * 96 + qjc + dw);

  const float* rnp = rnormS + si * 94 + sj0;
  float bestv = -3.0e38f; int bestsj = sj0;
  for (int it = 0; it < 47; ++it) {
    float a0 = 0.f, a1 = 0.f;
    #pragma unroll
    for (int k = 0; k < 9; ++k) {
      unsigned int u = (unsigned int)GT[off[k]];
      if (k & 1) a1 += __uint_as_float(u << 16);
      else       a0 += __uint_as_float(u << 16);
      off[k] += GTS;
    }
    float v = (a0 + a1) * rnp[it];
    if (v > bestv) { bestv = v; bestsj = sj0 + it; }
  }
  unsigned long long cand = 0ull;
  if (active) {
    int s = si * 94 + bestsj;
    cand = ((unsigned long long)ordf(bestv) << 32) |
           (unsigned long long)(0xFFFFFFFFu - (unsigned)s);
  }
  sm[halfv][qj] = cand;
  __syncthreads();
  if (t < 94) {
    unsigned long long c0 = sm[0][t], c1 = sm[1][t];
    unsigned long long c = c0 > c1 ? c0 : c1;    // pack: ties -> smaller s
    atomicMax(best + (size_t)(qi * 94 + t) * 8, c);
  }
}

// ---------------------------------------------------------------------------
// 3c) Fallback: R4 direct implicit-im2col GEMM+argmax (proven 265us path),
//     used when the workspace cannot hold GT.
// ---------------------------------------------------------------------------
__global__ __launch_bounds__(256, 2) void gemm_argmax_kernel(
    const unsigned char* __restrict__ TA, const unsigned char* __restrict__ TB,
    const float* __restrict__ rnormS, unsigned long long* __restrict__ best) {
  __shared__ unsigned char As[128 * 128];
  __shared__ unsigned char Bs[128 * 128];

  int orig = blockIdx.x;
  int xcd = orig & 7, idx = orig >> 3;
  int pid = (xcd < 4 ? xcd * 613 : 4 * 613 + (xcd - 4) * 612) + idx;

  int mt = pid % NTILE, nt = pid / NTILE;
  int q0 = mt * 128, s0 = nt * 128;
  int t = threadIdx.x, lane = t & 63, wave = t >> 6;
  int wm = wave >> 1, wn = wave & 1;

  int rr = t >> 3;
  int qc = (t & 7) ^ (rr & 7);
  const unsigned char* gA[4];
  const unsigned char* gB[4];
  #pragma unroll
  for (int i = 0; i < 4; ++i) {
    int qa = q0 + 32 * i + rr; if (qa > NP - 1) qa = NP - 1;
    int sa = s0 + 32 * i + rr; if (sa > NP - 1) sa = NP - 1;
    gA[i] = TA + (size_t)((qa / PW) * IW + (qa % PW)) * CH + qc * 16;
    gB[i] = TB + (size_t)((sa / PW) * IW + (sa % PW)) * CH + qc * 16;
  }
  unsigned char* lA = As + t * 16;
  unsigned char* lB = Bs + t * 16;

  f32x16 acc[2][2];
  #pragma unroll
  for (int mi = 0; mi < 2; ++mi)
    #pragma unroll
    for (int ni = 0; ni < 2; ++ni)
      #pragma unroll
      for (int j = 0; j < 16; ++j) acc[mi][ni][j] = 0.f;

  int kq = lane >> 5, sw = lane & 7;
  const unsigned char* Arow = As + (size_t)(wm * 64 + (lane & 31)) * 128;
  const unsigned char* Brow = Bs + (size_t)(wn * 64 + (lane & 31)) * 128;

  #pragma unroll 1
  for (int kt = 0; kt < KT2; ++kt) {
    int chunk = kt >> 1;
    int kh = chunk / 3, kw = chunk - kh * 3;
    int choff = (kh * IW + kw) * CH + (kt & 1) * 128;
    if (kt) __syncthreads();
    #pragma unroll
    for (int i = 0; i < 4; ++i) {
      gl16(gA[i] + choff, lA + i * 4096);
      gl16(gB[i] + choff, lB + i * 4096);
    }
    __syncthreads();
    #pragma unroll
    for (int h = 0; h < 2; ++h) {
      int c0 = 2 * kq + 4 * h;
      int o0 = (c0 ^ sw) * 16, o1 = ((c0 + 1) ^ sw) * 16;
      i32x8 af[2], bf[2];
      #pragma unroll
      for (int mi = 0; mi < 2; ++mi) af[mi] = ldfrag(Arow + mi * 32 * 128, o0, o1);
      #pragma unroll
      for (int ni = 0; ni < 2; ++ni) bf[ni] = ldfrag(Brow + ni * 32 * 128, o0, o1);
      #pragma unroll
      for (int mi = 0; mi < 2; ++mi)
        #pragma unroll
        for (int ni = 0; ni < 2; ++ni)
          acc[mi][ni] = __builtin_amdgcn_mfma_scale_f32_32x32x64_f8f6f4(
              af[mi], bf[ni], acc[mi][ni],
              0, 0, 0, 0x7F7F7F7F, 0, 0x7F7F7F7F);
    }
  }

  int col = lane & 31, half = lane >> 5;
  float rn[2]; int sc[2]; bool sv[2];
  #pragma unroll
  for (int ni = 0; ni < 2; ++ni) {
    int s = s0 + wn * 64 + ni * 32 + col;
    sc[ni] = s;
    sv[ni] = (s < NP);
    rn[ni] = sv[ni] ? rnormS[s] : 0.f;
  }
  #pragma unroll
  for (int mi = 0; mi < 2; ++mi) {
    #pragma unroll
    for (int reg = 0; reg < 16; ++reg) {
      unsigned long long p = 0ull;
      #pragma unroll
      for (int ni = 0; ni < 2; ++ni) {
        float v = acc[mi][ni][reg] * rn[ni];
        unsigned long long cand =
            ((unsigned long long)ordf(v) << 32) |
            (unsigned long long)(0xFFFFFFFFu - (unsigned)sc[ni]);
        cand = sv[ni] ? cand : 0ull;
        if (cand > p) p = cand;
      }
      #pragma unroll
      for (int sh = 16; sh >= 1; sh >>= 1) {
        unsigned long long o = __shfl_xor(p, sh, 64);
        if (o > p) p = o;
      }
      int q = q0 + wm * 64 + mi * 32 + (reg & 3) + 8 * (reg >> 2) + 4 * half;
      if (col == 0 && q < NP) atomicMax(best + (size_t)q * 8, p);
    }
  }
}

// ---------------------------------------------------------------------------
// 4) Final loss: loss = mean_q (synsq[q] - 2*dot + normsq[nn]) / 2304
// ---------------------------------------------------------------------------
__global__ void finalize_kernel(const unsigned long long* __restrict__ best,
                                const float* __restrict__ normS,
                                const float* __restrict__ normsqS,
                                const float* __restrict__ synsq,
                                float* __restrict__ out) {
  __shared__ float sm[256];
  int t = threadIdx.x;
  float accum = 0.f;
  for (int q = t; q < NP; q += 256) {
    unsigned long long p = best[(size_t)q * 8];
    unsigned int o   = (unsigned int)(p >> 32);
    unsigned int idx = 0xFFFFFFFFu - (unsigned int)(p & 0xFFFFFFFFull);
    unsigned int u   = (o & 0x80000000u) ? (o & 0x7FFFFFFFu) : ~o;
    float resp = __uint_as_float(u);
    float dot  = resp * normS[idx];
    accum += synsq[q] - 2.f * dot + normsqS[idx];
  }
  sm[t] = accum;
  __syncthreads();
  for (int s = 128; s >= 1; s >>= 1) {
    if (t < s) sm[t] += sm[t + s];
    __syncthreads();
  }
  if (t == 0) out[0] = sm[0] / ((float)NP * 2304.f);
}

// ---------------------------------------------------------------------------
extern "C" void kernel_launch(void* const* d_in, const int* in_sizes, int n_in,
                              void* d_out, int out_size, void* d_ws, size_t ws_size,
                              hipStream_t stream) {
  const float* inA = (const float*)d_in[0];  // input  (synthesis)
  const float* inB = (const float*)d_in[1];  // target (style)
  float* out = (float*)d_out;

  char* ws = (char*)d_ws;
  unsigned char* TA = (unsigned char*)ws;                 // 2,359,296 B fp8
  unsigned char* TB = (unsigned char*)(ws + 2359296);     // 2,359,296 B fp8
  float* rnormS  = (float*)(ws + 4718592);
  float* normS   = (float*)(ws + 4718592 + 35344);
  float* normsqS = (float*)(ws + 4718592 + 70688);
  float* synsq   = (float*)(ws + 4718592 + 106032);
  unsigned long long* best = (unsigned long long*)(ws + 4718592 + 141376);
  // best padded: 64 B per q -> 565,504 B. GT (bf16 9216x9216) follows.
  const size_t GT_OFF = 4718592ull + 141376ull + 565504ull;   // 5,425,472
  unsigned short* GT = (unsigned short*)(ws + GT_OFF);
  const size_t NEED = GT_OFF + (size_t)NPIX * NPIX * 2;       // 175,294,784

  (void)hipMemsetAsync(best, 0, (size_t)NP * 64, stream);
  prep_kernel<<<dim3(1152), dim3(256), 0, stream>>>(inA, inB, (unsigned int*)TA, (unsigned int*)TB);
  norms_kernel<<<dim3((2 * NP + 3) / 4), dim3(256), 0, stream>>>(
      (const unsigned int*)TA, (const unsigned int*)TB, rnormS, normS, normsqS, synsq);
  if (ws_size >= NEED) {
    g_gemm_kernel<<<dim3(72 * 72), dim3(256), 0, stream>>>(TA, TB, GT);
    tapsum_kernel<<<dim3(NP), dim3(256), 0, stream>>>(GT, rnormS, best);
  } else {
    gemm_argmax_kernel<<<dim3(NWG), dim3(256), 0, stream>>>(TA, TB, rnormS, best);
  }
  finalize_kernel<<<dim3(1), dim3(256), 0, stream>>>(best, normS, normsqS, synsq, out);
}

// Round 9
// 216.605 us; speedup vs baseline: 2.2529x; 1.2337x over previous
//
#include <hip/hip_runtime.h>
#include <math.h>

// Problem constants
#define NP 8836          // number of patches per image (94*94)
#define PW 94            // patches per row
#define IW 96            // image width/height
#define CH 256           // channels
#define NTILE 70         // ceil(8836/128)  (fallback GEMM)
#define KT2 18           // fallback K tiles
#define NWG (NTILE * NTILE)
#define NPIX 9216        // 96*96 pixels
#define GTS 9216         // GT row stride in elements

typedef int   i32x4  __attribute__((ext_vector_type(4)));
typedef int   i32x8  __attribute__((ext_vector_type(8)));
typedef float f32x16 __attribute__((ext_vector_type(16)));

__device__ __forceinline__ unsigned int ordf(float f) {
  unsigned int u = __float_as_uint(f);
  return (u & 0x80000000u) ? ~u : (u | 0x80000000u);
}

__device__ __forceinline__ float blo(unsigned int x) {   // low bf16 -> f32 (exact)
  return __uint_as_float(x << 16);
}
__device__ __forceinline__ float bhi(unsigned int x) {   // high bf16 -> f32 (exact)
  return __uint_as_float(x & 0xFFFF0000u);
}

typedef const __attribute__((address_space(1))) void GvoidC;
typedef __attribute__((address_space(3))) void Lvoid;
__device__ __forceinline__ void gl16(const void* g, void* l) {
  __builtin_amdgcn_global_load_lds((GvoidC*)g, (Lvoid*)l, 16, 0, 0);
}

// ---------------------------------------------------------------------------
// 1) Convert+transpose [C, 9216] fp32 -> [9216, C] fp8 (HW v_cvt encoding).
// ---------------------------------------------------------------------------
__global__ __launch_bounds__(256) void prep_kernel(
    const float* __restrict__ inA, const float* __restrict__ inB,
    unsigned int* __restrict__ TA, unsigned int* __restrict__ TB) {
  __shared__ float tile[64][65];
  int bid = blockIdx.x;            // [0, 1152)
  const float* src; unsigned int* dst;
  if (bid < 576) { src = inA; dst = TA; }
  else           { src = inB; dst = TB; bid -= 576; }
  int cT  = bid & 3;        // c-tile   [0,4)  (64 channels)
  int xyT = bid >> 2;       // xy-tile  [0,144)
  int t = threadIdx.x;
  int l = t & 63, h = t >> 6;

  #pragma unroll
  for (int i = 0; i < 16; ++i) {
    int c = h * 16 + i;
    tile[c][l] = src[(size_t)(cT * 64 + c) * (IW * IW) + xyT * 64 + l];
  }
  __syncthreads();
  int cu = t & 15;          // u32 column within the 64-channel tile
  #pragma unroll
  for (int i = 0; i < 4; ++i) {
    int xy = (t >> 4) + i * 16;
    int c = cu * 4;
    unsigned int v = __builtin_amdgcn_cvt_pk_fp8_f32(tile[c][xy],     tile[c + 1][xy], 0, false);
    v              = __builtin_amdgcn_cvt_pk_fp8_f32(tile[c + 2][xy], tile[c + 3][xy], v, true);
    dst[(size_t)(xyT * 64 + xy) * 64 + cT * 16 + cu] = v;
  }
}

// ---------------------------------------------------------------------------
// 2) Per-patch squared norms from the fp8 images (consistent with GEMM dtype).
// ---------------------------------------------------------------------------
__global__ void norms_kernel(const unsigned int* __restrict__ TA, const unsigned int* __restrict__ TB,
                             float* __restrict__ rnormS, float* __restrict__ normS,
                             float* __restrict__ normsqS, float* __restrict__ synsq) {
  int wid  = blockIdx.x * 4 + (threadIdx.x >> 6);
  int lane = threadIdx.x & 63;
  bool isStyle = wid < NP;
  int p = isStyle ? wid : wid - NP;
  if (p >= NP) return;
  const unsigned int* T = isStyle ? TB : TA;
  int pi = p / PW, pj = p % PW;
  float s = 0.f;
  #pragma unroll
  for (int kh = 0; kh < 3; ++kh) {
    #pragma unroll
    for (int kw = 0; kw < 3; ++kw) {
      unsigned int v = T[(size_t)((pi + kh) * IW + (pj + kw)) * 64 + lane];
      float f0 = __builtin_amdgcn_cvt_f32_fp8(v, 0);
      float f1 = __builtin_amdgcn_cvt_f32_fp8(v, 1);
      float f2 = __builtin_amdgcn_cvt_f32_fp8(v, 2);
      float f3 = __builtin_amdgcn_cvt_f32_fp8(v, 3);
      s += f0 * f0 + f1 * f1 + f2 * f2 + f3 * f3;
    }
  }
  #pragma unroll
  for (int m = 32; m >= 1; m >>= 1) s += __shfl_xor(s, m, 64);
  if (lane == 0) {
    if (isStyle) {
      normsqS[p] = s;
      float n = sqrtf(s);
      normS[p]  = n;
      rnormS[p] = 1.f / n;
    } else {
      synsq[p] = s;
    }
  }
}

__device__ __forceinline__ i32x8 ldfrag(const unsigned char* rowp, int o0, int o1) {
  i32x4 lo = *(const i32x4*)(rowp + o0);
  i32x4 hi = *(const i32x4*)(rowp + o1);
  return __builtin_shufflevector(lo, hi, 0, 1, 2, 3, 4, 5, 6, 7);
}

// ---------------------------------------------------------------------------
// 3a) G-path kernel 1: pixel Gram GT[y][x] = sum_ch TB[y][ch]*TA[x][ch],
//     M=N=9216, K=256 (2 BK=128 steps), 128x128 tiles (72x72 grid), bf16 out.
//     bf16 storage + all-f32 tap summation is the R6-PROVEN numerics
//     (absmax 0.0). R7/R8 lesson: do NOT change GT dtype or the tap load
//     mechanism to inline asm — both failed accuracy identically.
// ---------------------------------------------------------------------------
__global__ __launch_bounds__(256, 2) void g_gemm_kernel(
    const unsigned char* __restrict__ TA, const unsigned char* __restrict__ TB,
    unsigned short* __restrict__ GT) {
  __shared__ unsigned char As[128 * 128];
  __shared__ unsigned char Bs[128 * 128];

  // XCD-chunked bijective swizzle: 5184 = 8*648.
  int orig = blockIdx.x;
  int pid = (orig & 7) * 648 + (orig >> 3);
  int yt = pid % 72, xt = pid / 72;     // per-XCD chunk = 9 xt panels:
  int y0 = yt * 128, x0 = xt * 128;     // TB(2.4MB)+9 TA panels fit 4MB L2.
  int t = threadIdx.x, lane = t & 63, wave = t >> 6;
  int wm = wave >> 1, wn = wave & 1;

  int rr = t >> 3;
  int qc = (t & 7) ^ (rr & 7);
  const unsigned char* gA[4];
  const unsigned char* gB[4];
  #pragma unroll
  for (int i = 0; i < 4; ++i) {
    gA[i] = TB + (size_t)(y0 + 32 * i + rr) * CH + qc * 16;   // A-op = style y
    gB[i] = TA + (size_t)(x0 + 32 * i + rr) * CH + qc * 16;   // B-op = synth x
  }
  unsigned char* lA = As + t * 16;
  unsigned char* lB = Bs + t * 16;

  f32x16 acc[2][2];
  #pragma unroll
  for (int mi = 0; mi < 2; ++mi)
    #pragma unroll
    for (int ni = 0; ni < 2; ++ni)
      #pragma unroll
      for (int j = 0; j < 16; ++j) acc[mi][ni][j] = 0.f;

  int kq = lane >> 5, sw = lane & 7;
  const unsigned char* Arow = As + (size_t)(wm * 64 + (lane & 31)) * 128;
  const unsigned char* Brow = Bs + (size_t)(wn * 64 + (lane & 31)) * 128;

  #pragma unroll 1
  for (int kt = 0; kt < 2; ++kt) {
    int choff = kt * 128;
    if (kt) __syncthreads();
    #pragma unroll
    for (int i = 0; i < 4; ++i) {
      gl16(gA[i] + choff, lA + i * 4096);
      gl16(gB[i] + choff, lB + i * 4096);
    }
    __syncthreads();
    #pragma unroll
    for (int h = 0; h < 2; ++h) {
      int c0 = 2 * kq + 4 * h;
      int o0 = (c0 ^ sw) * 16, o1 = ((c0 + 1) ^ sw) * 16;
      i32x8 af[2], bf[2];
      #pragma unroll
      for (int mi = 0; mi < 2; ++mi) af[mi] = ldfrag(Arow + mi * 32 * 128, o0, o1);
      #pragma unroll
      for (int ni = 0; ni < 2; ++ni) bf[ni] = ldfrag(Brow + ni * 32 * 128, o0, o1);
      #pragma unroll
      for (int mi = 0; mi < 2; ++mi)
        #pragma unroll
        for (int ni = 0; ni < 2; ++ni)
          acc[mi][ni] = __builtin_amdgcn_mfma_scale_f32_32x32x64_f8f6f4(
              af[mi], bf[ni], acc[mi][ni],
              0, 0, 0, 0x7F7F7F7F, 0, 0x7F7F7F7F);
    }
  }

  // Epilogue: C/D (32x32): col = lane&31, row = (reg&3)+8*(reg>>2)+4*(lane>>5).
  // Store bf16 (RNE via integer round — R6-proven), coalesced ushort stores.
  int col = lane & 31, half = lane >> 5;
  #pragma unroll
  for (int mi = 0; mi < 2; ++mi) {
    #pragma unroll
    for (int ni = 0; ni < 2; ++ni) {
      size_t ybase = (size_t)(y0 + wm * 64 + mi * 32 + 4 * half);
      size_t xg    = (size_t)(x0 + wn * 64 + ni * 32 + col);
      unsigned short* p = GT + ybase * GTS + xg;
      #pragma unroll
      for (int g = 0; g < 4; ++g)
        #pragma unroll
        for (int j = 0; j < 4; ++j) {
          unsigned int u = __float_as_uint(acc[mi][ni][4 * g + j]);
          unsigned short b = (unsigned short)((u + 0x7FFFu + ((u >> 16) & 1u)) >> 16);
          p[(size_t)(j + 8 * g) * GTS] = b;
        }
    }
  }
}

// ---------------------------------------------------------------------------
// 3b) G-path kernel 2: tap-sum + argmax, v4 (plain HIP, qj-pairing).
//     resp[(qi,qj),(si,sj)] = sum_{dh,dw} GT[(si+dh)*96+sj+dw][(qi+dh)*96+qj+dw]
//     R6 v1 (PASSED, 145us): scalar ushort loads, ~52 VALU/output-iter.
//     R7/R8 (FAILED identically): inline-asm d16 pair loads — abandoned.
//     v4: each lane owns TWO adjacent qj (2l, 2l+1); per (dh) row-triple the
//     six taps for both outputs live at cols cb..cb+3 of rows r, r+1, r+2 ->
//     4 ALIGNED dword loads (E0@[r][cb], A@[r+1][cb], B@[r+1][cb+2],
//     C@[r+2][cb+2]). 12 dword loads + 9 stepped u32 offsets per 2 outputs
//     (vs 18 loads + 18 offsets), ~30 VALU/output vs 52.
//     Accumulation is BIT-IDENTICAL to R6 per output: a0 = t(0,0)+t(0,2)+
//     t(1,1)+t(2,0)+t(2,2) (in that order), a1 = t(0,1)+t(1,0)+t(1,2)+t(2,1),
//     v = (a0+a1)*rn -> identical resp, identical argmax, absmax 0.0.
//     Thread layout: 4 waves = 4 sj-groups (iters 12/12/12/11, wave-uniform);
//     lanes 0..46 own qj pairs (lane 47 clamped+masked; 48-63 idle).
// ---------------------------------------------------------------------------
__global__ __launch_bounds__(256) void tapsum_kernel(
    const unsigned short* __restrict__ GT, const float* __restrict__ rnormS,
    unsigned long long* __restrict__ best) {
  __shared__ unsigned long long sm[4][96];
  // XCD-chunked bijective swizzle (m204): nwg=8836, q=1104, r=4.
  int orig = blockIdx.x;
  int xcd = orig & 7, idx = orig >> 3;
  int pid = (xcd < 4 ? xcd * 1105 : 4 * 1105 + (xcd - 4) * 1104) + idx;
  // Diagonal-major: consecutive pid -> (qi+1, si+1): shares 2/3 G row-bands.
  int d = pid / 94, pos = pid - d * 94;
  int qi = pos;
  int si = pos + d; if (si >= 94) si -= 94;

  int t = threadIdx.x;
  int sjg = t >> 6, l = t & 63;          // sj-group = wave id (uniform)

  unsigned long long cand0 = 0ull, cand1 = 0ull;
  if (l < 48) {
    int lc = l < 47 ? l : 46;            // clamp keeps addresses in-bounds
    int sj0 = sjg * 12;
    int niter = (sjg == 3) ? 11 : 12;    // sj 36..46 for the last group

    // u32 element offsets, one per dh (dw=0 row); A/B/C derived by constants.
    unsigned int off0 = (unsigned)(((si + 0) * 96 + sj0) * GTS + (qi + 0) * 96 + 2 * lc);
    unsigned int off1 = (unsigned)(((si + 1) * 96 + sj0) * GTS + (qi + 1) * 96 + 2 * lc);
    unsigned int off2 = (unsigned)(((si + 2) * 96 + sj0) * GTS + (qi + 2) * 96 + 2 * lc);

    const float* rnp = rnormS + si * 94 + sj0;
    float bv0 = -3.0e38f, bv1 = -3.0e38f;
    int bs0 = sj0, bs1 = sj0;
    for (int j = 0; j < niter; ++j) {
      // dh = 0
      unsigned int e0_0 = *(const unsigned int*)(GT + off0);
      unsigned int a_0  = *(const unsigned int*)(GT + off0 + GTS);
      unsigned int b_0  = *(const unsigned int*)(GT + off0 + GTS + 2);
      unsigned int c_0  = *(const unsigned int*)(GT + off0 + 2 * GTS + 2);
      // dh = 1
      unsigned int e0_1 = *(const unsigned int*)(GT + off1);
      unsigned int a_1  = *(const unsigned int*)(GT + off1 + GTS);
      unsigned int b_1  = *(const unsigned int*)(GT + off1 + GTS + 2);
      unsigned int c_1  = *(const unsigned int*)(GT + off1 + 2 * GTS + 2);
      // dh = 2
      unsigned int e0_2 = *(const unsigned int*)(GT + off2);
      unsigned int a_2  = *(const unsigned int*)(GT + off2 + GTS);
      unsigned int b_2  = *(const unsigned int*)(GT + off2 + GTS + 2);
      unsigned int c_2  = *(const unsigned int*)(GT + off2 + 2 * GTS + 2);
      float rn = rnp[j];

      // Output 0 (qj = 2*lc): t(dh,0)=lo(E0), t(dh,1)=hi(A), t(dh,2)=lo(C).
      // R6 order: a0 = t00+t02+t11+t20+t22 ; a1 = t01+t10+t12+t21.
      float a0 = (((blo(e0_0) + blo(c_0)) + bhi(a_1)) + blo(e0_2)) + blo(c_2);
      float a1 = ((bhi(a_0) + blo(e0_1)) + blo(c_1)) + bhi(a_2);
      float v0 = (a0 + a1) * rn;
      // Output 1 (qj = 2*lc+1): t(dh,0)=hi(E0), t(dh,1)=lo(B), t(dh,2)=hi(C).
      float a0b = (((bhi(e0_0) + bhi(c_0)) + blo(b_1)) + bhi(e0_2)) + bhi(c_2);
      float a1b = ((blo(b_0) + bhi(e0_1)) + bhi(c_1)) + blo(b_2);
      float v1 = (a0b + a1b) * rn;

      int sj = sj0 + j;
      if (v0 > bv0) { bv0 = v0; bs0 = sj; }
      if (v1 > bv1) { bv1 = v1; bs1 = sj; }
      off0 += GTS; off1 += GTS; off2 += GTS;
    }
    if (2 * l < 94) {
      int s = si * 94 + bs0;
      cand0 = ((unsigned long long)ordf(bv0) << 32) |
              (unsigned long long)(0xFFFFFFFFu - (unsigned)s);
    }
    if (2 * l + 1 < 94) {
      int s = si * 94 + bs1;
      cand1 = ((unsigned long long)ordf(bv1) << 32) |
              (unsigned long long)(0xFFFFFFFFu - (unsigned)s);
    }
    sm[sjg][2 * l]     = cand0;
    sm[sjg][2 * l + 1] = cand1;
  }
  __syncthreads();
  if (t < 94) {
    unsigned long long c0 = sm[0][t], c1 = sm[1][t];
    unsigned long long c2 = sm[2][t], c3 = sm[3][t];
    unsigned long long ca = c0 > c1 ? c0 : c1;
    unsigned long long cb = c2 > c3 ? c2 : c3;
    unsigned long long c  = ca > cb ? ca : cb;   // ties -> smaller s (complement)
    atomicMax(best + (size_t)(qi * 94 + t) * 8, c);
  }
}

// ---------------------------------------------------------------------------
// 3c) Fallback: direct implicit-im2col GEMM+argmax (proven 265us path),
//     used when the workspace cannot hold GT.
// ---------------------------------------------------------------------------
__global__ __launch_bounds__(256, 2) void gemm_argmax_kernel(
    const unsigned char* __restrict__ TA, const unsigned char* __restrict__ TB,
    const float* __restrict__ rnormS, unsigned long long* __restrict__ best) {
  __shared__ unsigned char As[128 * 128];
  __shared__ unsigned char Bs[128 * 128];

  int orig = blockIdx.x;
  int xcd = orig & 7, idx = orig >> 3;
  int pid = (xcd < 4 ? xcd * 613 : 4 * 613 + (xcd - 4) * 612) + idx;

  int mt = pid % NTILE, nt = pid / NTILE;
  int q0 = mt * 128, s0 = nt * 128;
  int t = threadIdx.x, lane = t & 63, wave = t >> 6;
  int wm = wave >> 1, wn = wave & 1;

  int rr = t >> 3;
  int qc = (t & 7) ^ (rr & 7);
  const unsigned char* gA[4];
  const unsigned char* gB[4];
  #pragma unroll
  for (int i = 0; i < 4; ++i) {
    int qa = q0 + 32 * i + rr; if (qa > NP - 1) qa = NP - 1;
    int sa = s0 + 32 * i + rr; if (sa > NP - 1) sa = NP - 1;
    gA[i] = TA + (size_t)((qa / PW) * IW + (qa % PW)) * CH + qc * 16;
    gB[i] = TB + (size_t)((sa / PW) * IW + (sa % PW)) * CH + qc * 16;
  }
  unsigned char* lA = As + t * 16;
  unsigned char* lB = Bs + t * 16;

  f32x16 acc[2][2];
  #pragma unroll
  for (int mi = 0; mi < 2; ++mi)
    #pragma unroll
    for (int ni = 0; ni < 2; ++ni)
      #pragma unroll
      for (int j = 0; j < 16; ++j) acc[mi][ni][j] = 0.f;

  int kq = lane >> 5, sw = lane & 7;
  const unsigned char* Arow = As + (size_t)(wm * 64 + (lane & 31)) * 128;
  const unsigned char* Brow = Bs + (size_t)(wn * 64 + (lane & 31)) * 128;

  #pragma unroll 1
  for (int kt = 0; kt < KT2; ++kt) {
    int chunk = kt >> 1;
    int kh = chunk / 3, kw = chunk - kh * 3;
    int choff = (kh * IW + kw) * CH + (kt & 1) * 128;
    if (kt) __syncthreads();
    #pragma unroll
    for (int i = 0; i < 4; ++i) {
      gl16(gA[i] + choff, lA + i * 4096);
      gl16(gB[i] + choff, lB + i * 4096);
    }
    __syncthreads();
    #pragma unroll
    for (int h = 0; h < 2; ++h) {
      int c0 = 2 * kq + 4 * h;
      int o0 = (c0 ^ sw) * 16, o1 = ((c0 + 1) ^ sw) * 16;
      i32x8 af[2], bf[2];
      #pragma unroll
      for (int mi = 0; mi < 2; ++mi) af[mi] = ldfrag(Arow + mi * 32 * 128, o0, o1);
      #pragma unroll
      for (int ni = 0; ni < 2; ++ni) bf[ni] = ldfrag(Brow + ni * 32 * 128, o0, o1);
      #pragma unroll
      for (int mi = 0; mi < 2; ++mi)
        #pragma unroll
        for (int ni = 0; ni < 2; ++ni)
          acc[mi][ni] = __builtin_amdgcn_mfma_scale_f32_32x32x64_f8f6f4(
              af[mi], bf[ni], acc[mi][ni],
              0, 0, 0, 0x7F7F7F7F, 0, 0x7F7F7F7F);
    }
  }

  int col = lane & 31, half = lane >> 5;
  float rn[2]; int sc[2]; bool sv[2];
  #pragma unroll
  for (int ni = 0; ni < 2; ++ni) {
    int s = s0 + wn * 64 + ni * 32 + col;
    sc[ni] = s;
    sv[ni] = (s < NP);
    rn[ni] = sv[ni] ? rnormS[s] : 0.f;
  }
  #pragma unroll
  for (int mi = 0; mi < 2; ++mi) {
    #pragma unroll
    for (int reg = 0; reg < 16; ++reg) {
      unsigned long long p = 0ull;
      #pragma unroll
      for (int ni = 0; ni < 2; ++ni) {
        float v = acc[mi][ni][reg] * rn[ni];
        unsigned long long cand =
            ((unsigned long long)ordf(v) << 32) |
            (unsigned long long)(0xFFFFFFFFu - (unsigned)sc[ni]);
        cand = sv[ni] ? cand : 0ull;
        if (cand > p) p = cand;
      }
      #pragma unroll
      for (int sh = 16; sh >= 1; sh >>= 1) {
        unsigned long long o = __shfl_xor(p, sh, 64);
        if (o > p) p = o;
      }
      int q = q0 + wm * 64 + mi * 32 + (reg & 3) + 8 * (reg >> 2) + 4 * half;
      if (col == 0 && q < NP) atomicMax(best + (size_t)q * 8, p);
    }
  }
}

// ---------------------------------------------------------------------------
// 4) Final loss: loss = mean_q (synsq[q] - 2*dot + normsq[nn]) / 2304
// ---------------------------------------------------------------------------
__global__ void finalize_kernel(const unsigned long long* __restrict__ best,
                                const float* __restrict__ normS,
                                const float* __restrict__ normsqS,
                                const float* __restrict__ synsq,
                                float* __restrict__ out) {
  __shared__ float sm[256];
  int t = threadIdx.x;
  float accum = 0.f;
  for (int q = t; q < NP; q += 256) {
    unsigned long long p = best[(size_t)q * 8];
    unsigned int o   = (unsigned int)(p >> 32);
    unsigned int idx = 0xFFFFFFFFu - (unsigned int)(p & 0xFFFFFFFFull);
    unsigned int u   = (o & 0x80000000u) ? (o & 0x7FFFFFFFu) : ~o;
    float resp = __uint_as_float(u);
    float dot  = resp * normS[idx];
    accum += synsq[q] - 2.f * dot + normsqS[idx];
  }
  sm[t] = accum;
  __syncthreads();
  for (int s = 128; s >= 1; s >>= 1) {
    if (t < s) sm[t] += sm[t + s];
    __syncthreads();
  }
  if (t == 0) out[0] = sm[0] / ((float)NP * 2304.f);
}

// ---------------------------------------------------------------------------
extern "C" void kernel_launch(void* const* d_in, const int* in_sizes, int n_in,
                              void* d_out, int out_size, void* d_ws, size_t ws_size,
                              hipStream_t stream) {
  const float* inA = (const float*)d_in[0];  // input  (synthesis)
  const float* inB = (const float*)d_in[1];  // target (style)
  float* out = (float*)d_out;

  char* ws = (char*)d_ws;
  unsigned char* TA = (unsigned char*)ws;                 // 2,359,296 B fp8
  unsigned char* TB = (unsigned char*)(ws + 2359296);     // 2,359,296 B fp8
  float* rnormS  = (float*)(ws + 4718592);
  float* normS   = (float*)(ws + 4718592 + 35344);
  float* normsqS = (float*)(ws + 4718592 + 70688);
  float* synsq   = (float*)(ws + 4718592 + 106032);
  unsigned long long* best = (unsigned long long*)(ws + 4718592 + 141376);
  // best padded: 64 B per q -> 565,504 B. GT (bf16 9216x9216) follows.
  const size_t GT_OFF = 4718592ull + 141376ull + 565504ull;   // 5,425,472
  unsigned short* GT = (unsigned short*)(ws + GT_OFF);
  const size_t NEED = GT_OFF + (size_t)NPIX * NPIX * 2;       // 175,294,784

  (void)hipMemsetAsync(best, 0, (size_t)NP * 64, stream);
  prep_kernel<<<dim3(1152), dim3(256), 0, stream>>>(inA, inB, (unsigned int*)TA, (unsigned int*)TB);
  norms_kernel<<<dim3((2 * NP + 3) / 4), dim3(256), 0, stream>>>(
      (const unsigned int*)TA, (const unsigned int*)TB, rnormS, normS, normsqS, synsq);
  if (ws_size >= NEED) {
    g_gemm_kernel<<<dim3(72 * 72), dim3(256), 0, stream>>>(TA, TB, GT);
    tapsum_kernel<<<dim3(NP), dim3(256), 0, stream>>>(GT, rnormS, best);
  } else {
    gemm_argmax_kernel<<<dim3(NWG), dim3(256), 0, stream>>>(TA, TB, rnormS, best);
  }
  finalize_kernel<<<dim3(1), dim3(256), 0, stream>>>(best, normS, normsqS, synsq, out);
}